// Round 1
// baseline (1182.927 us; speedup 1.0000x reference)
//
#include <hip/hip_runtime.h>
#include <math.h>

#define L_LAYERS 2
#define H 1024
#define V 18
#define NUM_NODES 7
#define LEN 40
#define BATCH 512
#define NWG 256
#define NT 256

__device__ __forceinline__ float wred(float v) {
#pragma unroll
  for (int off = 32; off > 0; off >>= 1) v += __shfl_xor(v, off, 64);
  return v;
}

__device__ __forceinline__ float sigm(float x) { return 1.0f / (1.0f + expf(-x)); }

__device__ __forceinline__ void grid_barrier(unsigned* bar, unsigned target) {
  __syncthreads();
  if (threadIdx.x == 0) {
    __hip_atomic_fetch_add(bar, 1u, __ATOMIC_ACQ_REL, __HIP_MEMORY_SCOPE_AGENT);
    while (__hip_atomic_load(bar, __ATOMIC_ACQUIRE, __HIP_MEMORY_SCOPE_AGENT) < target) {
      __builtin_amdgcn_s_sleep(4);
    }
  }
  __syncthreads();
}

__global__ void __launch_bounds__(NT) init_ws_kernel(float* ws, int n) {
  int i = blockIdx.x * NT + threadIdx.x;
  if (i < n) ws[i] = 0.0f;
}

__global__ void __launch_bounds__(NT) decoder_kernel(
    const int* __restrict__ x0,
    const float* __restrict__ emb,    // [V][H]
    const float* __restrict__ w_ih,   // [L][4H][H]
    const float* __restrict__ w_hh,   // [L][4H][H]
    const float* __restrict__ b_ih,   // [L][4H]
    const float* __restrict__ b_hh,   // [L][4H]
    const float* __restrict__ w_fc,   // [V][H]
    const float* __restrict__ b_fc,   // [V]
    float* __restrict__ out,
    float* __restrict__ ws)
{
  float* h1buf = ws;            // [2][H] ping-pong
  float* h2buf = ws + 2 * H;    // [2][H]
  float* c1buf = ws + 4 * H;    // [H] (final-step c)
  float* c2buf = ws + 5 * H;    // [H]
  unsigned* bar = (unsigned*)(ws + 6 * H);

  float* out_tok  = out;                              // [LEN][BATCH] as float
  float* out_outs = out + LEN * BATCH;                // [BATCH][V]
  float* out_hf   = out + LEN * BATCH + BATCH * V;    // [2][BATCH][H]
  float* out_cf   = out_hf + L_LAYERS * BATCH * H;    // [2][BATCH][H]

  const int wg   = blockIdx.x;
  const int tid  = threadIdx.x;
  const int wave = tid >> 6;
  const int lane = tid & 63;
  const int j    = wg * 4 + wave;   // hidden unit owned by this wave (0..1023)

  __shared__ __align__(16) float s_in[H];
  __shared__ __align__(16) float s_h[H];
  __shared__ float s_logits[V];
  __shared__ int s_tok;
  __shared__ float s_lse;

  float c1 = 0.0f, c2 = 0.0f;
  int tok = x0[0];

  for (int t = 0; t < LEN; ++t) {
    const int pw = t & 1;       // write parity
    const int pr = pw ^ 1;      // read parity (prev step)

    // ---------------- Phase A: layer 0 ----------------
    {
      const float* inv = emb + (size_t)tok * H;
      const float* hpv = h1buf + pr * H;
      for (int i = tid; i < H / 4; i += NT) {
        ((float4*)s_in)[i] = ((const float4*)inv)[i];
        ((float4*)s_h)[i]  = ((const float4*)hpv)[i];
      }
      __syncthreads();
      float g4[4];
#pragma unroll
      for (int q = 0; q < 4; ++q) {
        const int row = q * H + j;
        const float4* wi = (const float4*)(w_ih + (size_t)row * H);
        const float4* wh = (const float4*)(w_hh + (size_t)row * H);
        float acc = 0.f;
#pragma unroll
        for (int m = 0; m < 4; ++m) {
          float4 a  = wi[lane + 64 * m];
          float4 xv = ((const float4*)s_in)[lane + 64 * m];
          float4 b  = wh[lane + 64 * m];
          float4 hv = ((const float4*)s_h)[lane + 64 * m];
          acc += a.x * xv.x + a.y * xv.y + a.z * xv.z + a.w * xv.w;
          acc += b.x * hv.x + b.y * hv.y + b.z * hv.z + b.w * hv.w;
        }
        acc = wred(acc);
        g4[q] = acc + b_ih[row] + b_hh[row];
      }
      float ig = sigm(g4[0]), fg = sigm(g4[1]);
      float gg = tanhf(g4[2]), og = sigm(g4[3]);
      c1 = fg * c1 + ig * gg;
      float hn = og * tanhf(c1);
      if (lane == 0) {
        h1buf[pw * H + j] = hn;
        if (t == LEN - 1) c1buf[j] = c1;
      }
    }
    grid_barrier(bar, (unsigned)(t * 2 + 1) * NWG);

    // ---------------- Phase B: layer 1 ----------------
    {
      const float* inv = h1buf + pw * H;
      const float* hpv = h2buf + pr * H;
      for (int i = tid; i < H / 4; i += NT) {
        ((float4*)s_in)[i] = ((const float4*)inv)[i];
        ((float4*)s_h)[i]  = ((const float4*)hpv)[i];
      }
      __syncthreads();
      const float* wi1 = w_ih + (size_t)4 * H * H;
      const float* wh1 = w_hh + (size_t)4 * H * H;
      const float* bi1 = b_ih + 4 * H;
      const float* bh1 = b_hh + 4 * H;
      float g4[4];
#pragma unroll
      for (int q = 0; q < 4; ++q) {
        const int row = q * H + j;
        const float4* wi = (const float4*)(wi1 + (size_t)row * H);
        const float4* wh = (const float4*)(wh1 + (size_t)row * H);
        float acc = 0.f;
#pragma unroll
        for (int m = 0; m < 4; ++m) {
          float4 a  = wi[lane + 64 * m];
          float4 xv = ((const float4*)s_in)[lane + 64 * m];
          float4 b  = wh[lane + 64 * m];
          float4 hv = ((const float4*)s_h)[lane + 64 * m];
          acc += a.x * xv.x + a.y * xv.y + a.z * xv.z + a.w * xv.w;
          acc += b.x * hv.x + b.y * hv.y + b.z * hv.z + b.w * hv.w;
        }
        acc = wred(acc);
        g4[q] = acc + bi1[row] + bh1[row];
      }
      float ig = sigm(g4[0]), fg = sigm(g4[1]);
      float gg = tanhf(g4[2]), og = sigm(g4[3]);
      c2 = fg * c2 + ig * gg;
      float hn = og * tanhf(c2);
      if (lane == 0) {
        h2buf[pw * H + j] = hn;
        if (t == LEN - 1) c2buf[j] = c2;
      }
    }
    grid_barrier(bar, (unsigned)(t * 2 + 2) * NWG);

    // ---------------- Phase C: fc + argmax (redundant in every WG) ----------------
    {
      const float* h2v = h2buf + pw * H;
      for (int i = tid; i < H / 4; i += NT) {
        ((float4*)s_in)[i] = ((const float4*)h2v)[i];
      }
      __syncthreads();
      for (int v = wave; v < V; v += 4) {
        const float4* wf = (const float4*)(w_fc + (size_t)v * H);
        float acc = 0.f;
#pragma unroll
        for (int m = 0; m < 4; ++m) {
          float4 a  = wf[lane + 64 * m];
          float4 hv = ((const float4*)s_in)[lane + 64 * m];
          acc += a.x * hv.x + a.y * hv.y + a.z * hv.z + a.w * hv.w;
        }
        acc = wred(acc);
        if (lane == 0) s_logits[v] = acc + b_fc[v];
      }
      __syncthreads();
      if (tid == 0) {
        const int node_end = ((t >> 1) % 10) / 2 + 3;
        float bv = -INFINITY;
        int bi = 0;
        for (int v = 0; v < V; ++v) {
          bool m = (t & 1) ? (v >= NUM_NODES) : (v >= 1 && v < node_end);
          if (m && s_logits[v] > bv) { bv = s_logits[v]; bi = v; }
        }
        s_tok = bi;
      }
      __syncthreads();
      tok = s_tok;

      if (wg == 0) {
        const float tf = (float)tok;
        for (int b = tid; b < BATCH; b += NT) out_tok[t * BATCH + b] = tf;
        if (t == LEN - 1) {
          if (tid == 0) {
            float mx = -INFINITY;
            for (int v = 0; v < V; ++v) mx = fmaxf(mx, s_logits[v]);
            float s = 0.f;
            for (int v = 0; v < V; ++v) s += expf(s_logits[v] - mx);
            s_lse = mx + logf(s);
          }
          __syncthreads();
          for (int i = tid; i < BATCH * V; i += NT) {
            out_outs[i] = s_logits[i % V] - s_lse;
          }
        }
      }
    }
  }

  // ---------------- Final: broadcast h_f, c_f ----------------
  grid_barrier(bar, (unsigned)(2 * LEN + 1) * NWG);
  const int pf = (LEN - 1) & 1;
  for (int r = wg; r < L_LAYERS * BATCH; r += NWG) {
    const int l = r >> 9;  // r / 512
    const float* hsrc = (l == 0 ? h1buf : h2buf) + pf * H;
    const float* csrc = (l == 0 ? c1buf : c2buf);
    float4* hd = (float4*)(out_hf + (size_t)r * H);
    float4* cd = (float4*)(out_cf + (size_t)r * H);
    for (int i = tid; i < H / 4; i += NT) {
      hd[i] = ((const float4*)hsrc)[i];
      cd[i] = ((const float4*)csrc)[i];
    }
  }
}

extern "C" void kernel_launch(void* const* d_in, const int* in_sizes, int n_in,
                              void* d_out, int out_size, void* d_ws, size_t ws_size,
                              hipStream_t stream) {
  const int*   x0   = (const int*)d_in[0];
  const float* emb  = (const float*)d_in[1];
  const float* w_ih = (const float*)d_in[2];
  const float* w_hh = (const float*)d_in[3];
  const float* b_ih = (const float*)d_in[4];
  const float* b_hh = (const float*)d_in[5];
  const float* w_fc = (const float*)d_in[6];
  const float* b_fc = (const float*)d_in[7];
  float* ws = (float*)d_ws;

  // zero h ping-pong buffers + c buffers + barrier counter (ws is poisoned 0xAA)
  hipLaunchKernelGGL(init_ws_kernel, dim3(32), dim3(NT), 0, stream, ws, 8192);
  hipLaunchKernelGGL(decoder_kernel, dim3(NWG), dim3(NT), 0, stream,
                     x0, emb, w_ih, w_hh, b_ih, b_hh, w_fc, b_fc,
                     (float*)d_out, ws);
}

// Round 2
// 865.347 us; speedup vs baseline: 1.3670x; 1.3670x over previous
//
#include <hip/hip_runtime.h>
#include <math.h>

#define H 1024
#define V 18
#define NUM_NODES 7
#define LEN 40
#define BATCH 512
#define NWG 256
#define NT 1024
#define FSTRIDE 16  // unsigneds between flags (64B padding)

// ws layout (floats):
//   0      h1buf [2][H]
//   2048   h2buf [2][H]
//   4096   c1buf [H]
//   5120   c2buf [H]
//   6144   flags [NWG * FSTRIDE] (as unsigned)
//   10240  rel   [16]            (as unsigned)
#define WS_ZERO_N 10256

__device__ __forceinline__ float wred(float v) {
#pragma unroll
  for (int off = 32; off > 0; off >>= 1) v += __shfl_xor(v, off, 64);
  return v;
}
__device__ __forceinline__ float sigm(float x) { return 1.0f / (1.0f + expf(-x)); }
__device__ __forceinline__ float dot4(float4 a, float4 b) {
  return a.x * b.x + a.y * b.y + a.z * b.z + a.w * b.w;
}

__device__ __forceinline__ void grid_barrier(unsigned* flags, unsigned* rel,
                                             int wg, int tid, int lane, int wave,
                                             unsigned k) {
  __syncthreads();
  if (tid == 0) {
    __hip_atomic_store(&flags[wg * FSTRIDE], k, __ATOMIC_RELEASE, __HIP_MEMORY_SCOPE_AGENT);
  }
  if (wg == 0) {
    if (wave == 0) {
      for (;;) {
        bool ok = true;
#pragma unroll
      for (int m = 0; m < 4; ++m) {
          unsigned f = __hip_atomic_load(&flags[(lane + 64 * m) * FSTRIDE],
                                         __ATOMIC_RELAXED, __HIP_MEMORY_SCOPE_AGENT);
          ok &= (f >= k);
        }
        if (__all(ok)) break;
        __builtin_amdgcn_s_sleep(1);
      }
      __builtin_amdgcn_fence(__ATOMIC_ACQUIRE, "agent");
      if (lane == 0)
        __hip_atomic_store(rel, k, __ATOMIC_RELEASE, __HIP_MEMORY_SCOPE_AGENT);
    }
  } else {
    if (tid == 0) {
      while (__hip_atomic_load(rel, __ATOMIC_RELAXED, __HIP_MEMORY_SCOPE_AGENT) < k) {
        __builtin_amdgcn_s_sleep(1);
      }
      __builtin_amdgcn_fence(__ATOMIC_ACQUIRE, "agent");
    }
  }
  __syncthreads();
}

__global__ void __launch_bounds__(256) init_ws_kernel(float* ws, int n) {
  int i = blockIdx.x * 256 + threadIdx.x;
  if (i < n) ws[i] = 0.0f;
}

__global__ void __launch_bounds__(NT, 4) decoder_kernel(
    const int* __restrict__ x0,
    const float* __restrict__ emb,    // [V][H]
    const float* __restrict__ w_ih,   // [L][4H][H]
    const float* __restrict__ w_hh,   // [L][4H][H]
    const float* __restrict__ b_ih,   // [L][4H]
    const float* __restrict__ b_hh,   // [L][4H]
    const float* __restrict__ w_fc,   // [V][H]
    const float* __restrict__ b_fc,   // [V]
    float* __restrict__ out,
    float* __restrict__ ws)
{
  float* h1buf = ws;
  float* h2buf = ws + 2 * H;
  float* c1buf = ws + 4 * H;
  float* c2buf = ws + 5 * H;
  unsigned* flags = (unsigned*)(ws + 6 * H);
  unsigned* rel   = (unsigned*)(ws + 6 * H + NWG * FSTRIDE);

  float* out_tok  = out;                           // [LEN][BATCH] (as float)
  float* out_outs = out + LEN * BATCH;             // [BATCH][V]
  float* out_hf   = out_outs + BATCH * V;          // [2][BATCH][H]
  float* out_cf   = out_hf + 2 * BATCH * H;        // [2][BATCH][H]

  const int wg = blockIdx.x, tid = threadIdx.x;
  const int wave = tid >> 6, lane = tid & 63;
  const int q = wave & 3;          // gate index (i,f,g,o)
  const int u = wave >> 2;         // unit-within-WG (0..3)
  const int j = wg * 4 + u;        // hidden unit (0..1023)
  const int row = q * H + j;       // gate row within a layer

  // ---- persistent weights in registers: 2 rows x 2 matrices = 64 VGPRs ----
  float4 wi0[4], wh0[4], wi1[4], wh1[4];
  {
    const float4* p0 = (const float4*)(w_ih + (size_t)row * H);
    const float4* p1 = (const float4*)(w_hh + (size_t)row * H);
    const float4* p2 = (const float4*)(w_ih + (size_t)(4 * H + row) * H);
    const float4* p3 = (const float4*)(w_hh + (size_t)(4 * H + row) * H);
#pragma unroll
    for (int m = 0; m < 4; ++m) {
      wi0[m] = p0[lane + 64 * m];
      wh0[m] = p1[lane + 64 * m];
      wi1[m] = p2[lane + 64 * m];
      wh1[m] = p3[lane + 64 * m];
    }
  }
  const float bsum0 = b_ih[row] + b_hh[row];
  const float bsum1 = b_ih[4 * H + row] + b_hh[4 * H + row];

  __shared__ float s_g1[4][4];
  __shared__ float s_g2[4][4];
  __shared__ float s_c1[4], s_c2[4];
  __shared__ float s_logits[V];
  __shared__ int s_tok;
  __shared__ float s_lse;
  if (tid < 4) { s_c1[tid] = 0.f; s_c2[tid] = 0.f; }  // read only by same thread

  int tok = x0[0];
  unsigned k = 0;

  for (int t = 0; t < LEN; ++t) {
    const int pw = t & 1, pr = pw ^ 1;

    // ---------------- Phase A: layer 0 ----------------
    {
      const float4* inr = (const float4*)(emb + (size_t)tok * H);
      const float4* hr  = (const float4*)(h1buf + pr * H);
      float acc = 0.f;
#pragma unroll
      for (int m = 0; m < 4; ++m) {
        acc += dot4(wi0[m], inr[lane + 64 * m]);
        acc += dot4(wh0[m], hr[lane + 64 * m]);
      }
      acc = wred(acc);
      if (lane == 0) s_g1[u][q] = acc + bsum0;
      __syncthreads();
      if (tid < 4) {
        const int uu = tid, jj = wg * 4 + uu;
        float ig = sigm(s_g1[uu][0]), fg = sigm(s_g1[uu][1]);
        float gg = tanhf(s_g1[uu][2]), og = sigm(s_g1[uu][3]);
        float c = fg * s_c1[uu] + ig * gg;
        s_c1[uu] = c;
        float hn = og * tanhf(c);
        h1buf[pw * H + jj] = hn;
        if (t == LEN - 1) c1buf[jj] = c;
      }
    }
    grid_barrier(flags, rel, wg, tid, lane, wave, ++k);

    // ---------------- Phase B: layer 1 ----------------
    {
      const float4* inr = (const float4*)(h1buf + pw * H);
      const float4* hr  = (const float4*)(h2buf + pr * H);
      float acc = 0.f;
#pragma unroll
      for (int m = 0; m < 4; ++m) {
        acc += dot4(wi1[m], inr[lane + 64 * m]);
        acc += dot4(wh1[m], hr[lane + 64 * m]);
      }
      acc = wred(acc);
      if (lane == 0) s_g2[u][q] = acc + bsum1;
      __syncthreads();
      if (tid < 4) {
        const int uu = tid, jj = wg * 4 + uu;
        float ig = sigm(s_g2[uu][0]), fg = sigm(s_g2[uu][1]);
        float gg = tanhf(s_g2[uu][2]), og = sigm(s_g2[uu][3]);
        float c = fg * s_c2[uu] + ig * gg;
        s_c2[uu] = c;
        float hn = og * tanhf(c);
        h2buf[pw * H + jj] = hn;
        if (t == LEN - 1) c2buf[jj] = c;
      }
    }
    grid_barrier(flags, rel, wg, tid, lane, wave, ++k);

    // ---------------- Phase C: fc + argmax (redundant per WG) ----------------
    {
      const float4* h2r = (const float4*)(h2buf + pw * H);
      float4 hv[4];
#pragma unroll
      for (int m = 0; m < 4; ++m) hv[m] = h2r[lane + 64 * m];
      if (wave < 16) {
        const float4* wf = (const float4*)(w_fc + (size_t)wave * H);
        float acc = 0.f;
#pragma unroll
        for (int m = 0; m < 4; ++m) acc += dot4(wf[lane + 64 * m], hv[m]);
        acc = wred(acc);
        if (lane == 0) s_logits[wave] = acc + b_fc[wave];
      }
      if (wave < 2) {
        const int v2 = 16 + wave;
        const float4* wf = (const float4*)(w_fc + (size_t)v2 * H);
        float acc = 0.f;
#pragma unroll
        for (int m = 0; m < 4; ++m) acc += dot4(wf[lane + 64 * m], hv[m]);
        acc = wred(acc);
        if (lane == 0) s_logits[v2] = acc + b_fc[v2];
      }
      __syncthreads();
      if (tid == 0) {
        const int node_end = ((t >> 1) % 10) / 2 + 3;
        float bv = -INFINITY;
        int bi = 0;
        for (int v = 0; v < V; ++v) {
          bool m = (t & 1) ? (v >= NUM_NODES) : (v >= 1 && v < node_end);
          if (m && s_logits[v] > bv) { bv = s_logits[v]; bi = v; }
        }
        s_tok = bi;
      }
      __syncthreads();
      tok = s_tok;

      if (wg == 0) {
        if (tid < BATCH) out_tok[t * BATCH + tid] = (float)tok;
        if (t == LEN - 1) {
          if (tid == 0) {
            float mx = -INFINITY;
            for (int v = 0; v < V; ++v) mx = fmaxf(mx, s_logits[v]);
            float s = 0.f;
            for (int v = 0; v < V; ++v) s += expf(s_logits[v] - mx);
            s_lse = mx + logf(s);
          }
          __syncthreads();
          for (int i = tid; i < BATCH * V; i += NT)
            out_outs[i] = s_logits[i % V] - s_lse;
        }
      }
    }
  }

  // ---------------- Final: broadcast h_f, c_f ----------------
  grid_barrier(flags, rel, wg, tid, lane, wave, ++k);
  const int pf = (LEN - 1) & 1;
  // 2*BATCH rows of H; 4 rows per WG; one float4 of h and c per thread
  for (int z = tid; z < 4 * (H / 4); z += NT) {
    const int rr = z >> 8;          // 0..3
    const int i  = z & 255;         // float4 index within row
    const int r  = wg + rr * NWG;   // row in [0, 1024)
    const int l  = r >> 9;          // layer
    const float* hsrc = (l == 0 ? h1buf : h2buf) + pf * H;
    const float* csrc = (l == 0 ? c1buf : c2buf);
    ((float4*)(out_hf + (size_t)r * H))[i] = ((const float4*)hsrc)[i];
    ((float4*)(out_cf + (size_t)r * H))[i] = ((const float4*)csrc)[i];
  }
}

extern "C" void kernel_launch(void* const* d_in, const int* in_sizes, int n_in,
                              void* d_out, int out_size, void* d_ws, size_t ws_size,
                              hipStream_t stream) {
  const int*   x0   = (const int*)d_in[0];
  const float* emb  = (const float*)d_in[1];
  const float* w_ih = (const float*)d_in[2];
  const float* w_hh = (const float*)d_in[3];
  const float* b_ih = (const float*)d_in[4];
  const float* b_hh = (const float*)d_in[5];
  const float* w_fc = (const float*)d_in[6];
  const float* b_fc = (const float*)d_in[7];
  float* ws = (float*)d_ws;

  hipLaunchKernelGGL(init_ws_kernel, dim3((WS_ZERO_N + 255) / 256), dim3(256), 0, stream,
                     ws, WS_ZERO_N);
  hipLaunchKernelGGL(decoder_kernel, dim3(NWG), dim3(NT), 0, stream,
                     x0, emb, w_ih, w_hh, b_ih, b_hh, w_fc, b_fc,
                     (float*)d_out, ws);
}

// Round 3
// 486.353 us; speedup vs baseline: 2.4322x; 1.7793x over previous
//
#include <hip/hip_runtime.h>
#include <math.h>

#define H 1024
#define V 18
#define NUM_NODES 7
#define LEN 40
#define BATCH 512
#define NWG 256
#define NT 1024
#define FSTRIDE 16  // unsigneds between flags (64B padding)

// ws layout (floats):
//   0      h1buf [2][H]
//   2048   h2buf [2][H]
//   4096   c1buf [H]
//   5120   c2buf [H]
//   6144   flags [NWG * FSTRIDE] (as unsigned)
#define WS_ZERO_N (6 * H + NWG * FSTRIDE)

#define AGENT __HIP_MEMORY_SCOPE_AGENT

__device__ __forceinline__ float wred(float v) {
#pragma unroll
  for (int off = 32; off > 0; off >>= 1) v += __shfl_xor(v, off, 64);
  return v;
}
__device__ __forceinline__ float sigm(float x) { return 1.0f / (1.0f + expf(-x)); }
__device__ __forceinline__ float dot4(float4 a, float4 b) {
  return a.x * b.x + a.y * b.y + a.z * b.z + a.w * b.w;
}

// Fence-free grid barrier: relaxed agent atomics only; ordering by vmcnt drain.
// wave 0: drain stores -> publish flag -> poll all 256 flags. Then WG-wide sync.
__device__ __forceinline__ void grid_barrier(unsigned* flags, int wg, int lane,
                                             int wave, unsigned k) {
  if (wave == 0) {
    asm volatile("s_waitcnt vmcnt(0)" ::: "memory");
    if (lane == 0)
      __hip_atomic_store(&flags[wg * FSTRIDE], k, __ATOMIC_RELAXED, AGENT);
    for (;;) {
      bool ok = true;
#pragma unroll
      for (int m = 0; m < 4; ++m) {
        unsigned f = __hip_atomic_load(&flags[(lane + 64 * m) * FSTRIDE],
                                       __ATOMIC_RELAXED, AGENT);
        ok &= (f >= k);
      }
      if (__all(ok)) break;
      __builtin_amdgcn_s_sleep(1);
    }
    asm volatile("" ::: "memory");
  }
  __syncthreads();
}

__global__ void __launch_bounds__(256) init_ws_kernel(float* ws, int n) {
  int i = blockIdx.x * 256 + threadIdx.x;
  if (i < n) ws[i] = 0.0f;
}

__global__ void __launch_bounds__(NT, 4) decoder_kernel(
    const int* __restrict__ x0,
    const float* __restrict__ emb,    // [V][H]
    const float* __restrict__ w_ih,   // [L][4H][H]
    const float* __restrict__ w_hh,   // [L][4H][H]
    const float* __restrict__ b_ih,   // [L][4H]
    const float* __restrict__ b_hh,   // [L][4H]
    const float* __restrict__ w_fc,   // [V][H]
    const float* __restrict__ b_fc,   // [V]
    float* __restrict__ out,
    float* __restrict__ ws)
{
  float* h1buf = ws;
  float* h2buf = ws + 2 * H;
  float* c1buf = ws + 4 * H;
  float* c2buf = ws + 5 * H;
  unsigned* flags = (unsigned*)(ws + 6 * H);

  float* out_tok  = out;                           // [LEN][BATCH] (as float)
  float* out_outs = out + LEN * BATCH;             // [BATCH][V]
  float* out_hf   = out_outs + BATCH * V;          // [2][BATCH][H]
  float* out_cf   = out_hf + 2 * BATCH * H;        // [2][BATCH][H]

  const int wg = blockIdx.x, tid = threadIdx.x;
  const int wave = tid >> 6, lane = tid & 63;
  const int q = wave & 3;          // gate index (i,f,g,o)
  const int u = wave >> 2;         // unit-within-WG (0..3)
  const int j = wg * 4 + u;        // hidden unit (0..1023)
  const int row = q * H + j;       // gate row within a layer

  // ---- persistent weights in registers: 2 rows x 2 matrices = 64 VGPRs ----
  float4 wi0[4], wh0[4], wi1[4], wh1[4];
  {
    const float4* p0 = (const float4*)(w_ih + (size_t)row * H);
    const float4* p1 = (const float4*)(w_hh + (size_t)row * H);
    const float4* p2 = (const float4*)(w_ih + (size_t)(4 * H + row) * H);
    const float4* p3 = (const float4*)(w_hh + (size_t)(4 * H + row) * H);
#pragma unroll
    for (int m = 0; m < 4; ++m) {
      wi0[m] = p0[lane + 64 * m];
      wh0[m] = p1[lane + 64 * m];
      wi1[m] = p2[lane + 64 * m];
      wh1[m] = p3[lane + 64 * m];
    }
  }
  const float bsum0 = b_ih[row] + b_hh[row];
  const float bsum1 = b_ih[4 * H + row] + b_hh[4 * H + row];

  __shared__ __align__(16) float s_h1[H];   // current h1 (staged)
  __shared__ __align__(16) float s_h2[H];   // current h2 (staged)
  __shared__ float s_g1[4][4];
  __shared__ float s_g2[4][4];
  __shared__ float s_c1[4], s_c2[4];
  __shared__ float s_logits[V];
  __shared__ int s_tok;
  __shared__ float s_lse;

  s_h1[tid] = 0.0f;
  s_h2[tid] = 0.0f;
  if (tid < 4) { s_c1[tid] = 0.f; s_c2[tid] = 0.f; }
  __syncthreads();

  int tok = x0[0];

  for (int t = 0; t < LEN; ++t) {
    const int pw = t & 1;

    // ---------------- Phase A: layer 0 (reads s_h1 = h1(t-1)) ----------------
    {
      const float4* er = (const float4*)(emb + (size_t)tok * H);
      float acc = 0.f;
#pragma unroll
      for (int m = 0; m < 4; ++m) {
        acc += dot4(wi0[m], er[lane + 64 * m]);
        acc += dot4(wh0[m], ((const float4*)s_h1)[lane + 64 * m]);
      }
      acc = wred(acc);
      if (lane == 0) s_g1[u][q] = acc + bsum0;
      __syncthreads();
      if (tid < 4) {
        const int uu = tid, jj = wg * 4 + uu;
        float ig = sigm(s_g1[uu][0]), fg = sigm(s_g1[uu][1]);
        float gg = tanhf(s_g1[uu][2]), og = sigm(s_g1[uu][3]);
        float c = fg * s_c1[uu] + ig * gg;
        s_c1[uu] = c;
        float hn = og * tanhf(c);
        __hip_atomic_store(&h1buf[pw * H + jj], hn, __ATOMIC_RELAXED, AGENT);
        if (t == LEN - 1)
          __hip_atomic_store(&c1buf[jj], c, __ATOMIC_RELAXED, AGENT);
      }
    }
    grid_barrier(flags, wg, lane, wave, (unsigned)(2 * t + 1));
    s_h1[tid] = __hip_atomic_load(&h1buf[pw * H + tid], __ATOMIC_RELAXED, AGENT);
    __syncthreads();

    // ---------------- Phase B: layer 1 (reads s_h1 = h1(t), s_h2 = h2(t-1)) ----
    {
      float acc = 0.f;
#pragma unroll
      for (int m = 0; m < 4; ++m) {
        acc += dot4(wi1[m], ((const float4*)s_h1)[lane + 64 * m]);
        acc += dot4(wh1[m], ((const float4*)s_h2)[lane + 64 * m]);
      }
      acc = wred(acc);
      if (lane == 0) s_g2[u][q] = acc + bsum1;
      __syncthreads();
      if (tid < 4) {
        const int uu = tid, jj = wg * 4 + uu;
        float ig = sigm(s_g2[uu][0]), fg = sigm(s_g2[uu][1]);
        float gg = tanhf(s_g2[uu][2]), og = sigm(s_g2[uu][3]);
        float c = fg * s_c2[uu] + ig * gg;
        s_c2[uu] = c;
        float hn = og * tanhf(c);
        __hip_atomic_store(&h2buf[pw * H + jj], hn, __ATOMIC_RELAXED, AGENT);
        if (t == LEN - 1)
          __hip_atomic_store(&c2buf[jj], c, __ATOMIC_RELAXED, AGENT);
      }
    }
    grid_barrier(flags, wg, lane, wave, (unsigned)(2 * t + 2));
    s_h2[tid] = __hip_atomic_load(&h2buf[pw * H + tid], __ATOMIC_RELAXED, AGENT);
    __syncthreads();

    // ---------------- Phase C: fc + argmax (redundant per WG, no barrier) -----
    {
      if (wave < 16) {
        const float4* wf = (const float4*)(w_fc + (size_t)wave * H);
        float acc = 0.f;
#pragma unroll
        for (int m = 0; m < 4; ++m)
          acc += dot4(wf[lane + 64 * m], ((const float4*)s_h2)[lane + 64 * m]);
        acc = wred(acc);
        if (lane == 0) s_logits[wave] = acc + b_fc[wave];
      }
      if (wave < 2) {
        const int v2 = 16 + wave;
        const float4* wf = (const float4*)(w_fc + (size_t)v2 * H);
        float acc = 0.f;
#pragma unroll
        for (int m = 0; m < 4; ++m)
          acc += dot4(wf[lane + 64 * m], ((const float4*)s_h2)[lane + 64 * m]);
        acc = wred(acc);
        if (lane == 0) s_logits[v2] = acc + b_fc[v2];
      }
      __syncthreads();
      if (tid == 0) {
        const int node_end = ((t >> 1) % 10) / 2 + 3;
        float bv = -INFINITY;
        int bi = 0;
        for (int v = 0; v < V; ++v) {
          bool m = (t & 1) ? (v >= NUM_NODES) : (v >= 1 && v < node_end);
          if (m && s_logits[v] > bv) { bv = s_logits[v]; bi = v; }
        }
        s_tok = bi;
      }
      __syncthreads();
      tok = s_tok;

      if (wg == 0) {
        if (tid < BATCH) out_tok[t * BATCH + tid] = (float)tok;
        if (t == LEN - 1) {
          if (tid == 0) {
            float mx = -INFINITY;
            for (int v = 0; v < V; ++v) mx = fmaxf(mx, s_logits[v]);
            float s = 0.f;
            for (int v = 0; v < V; ++v) s += expf(s_logits[v] - mx);
            s_lse = mx + logf(s);
          }
          __syncthreads();
          for (int i = tid; i < BATCH * V; i += NT)
            out_outs[i] = s_logits[i % V] - s_lse;
        }
      }
    }
  }

  // ---------------- Final: broadcast h_f, c_f ----------------
  // s_h1 holds h1(39), s_h2 holds h2(39); c already published (synced by barrier 80).
  for (int z = tid; z < 4 * (H / 4); z += NT) {
    const int rr = z >> 8;          // 0..3
    const int i  = z & 255;         // float4 index within row
    const int r  = wg + rr * NWG;   // row in [0, 1024)
    const float* hsrc = (r >> 9) == 0 ? s_h1 : s_h2;
    ((float4*)(out_hf + (size_t)r * H))[i] = ((const float4*)hsrc)[i];
  }
  __syncthreads();
  s_h1[tid] = __hip_atomic_load(&c1buf[tid], __ATOMIC_RELAXED, AGENT);
  s_h2[tid] = __hip_atomic_load(&c2buf[tid], __ATOMIC_RELAXED, AGENT);
  __syncthreads();
  for (int z = tid; z < 4 * (H / 4); z += NT) {
    const int rr = z >> 8;
    const int i  = z & 255;
    const int r  = wg + rr * NWG;
    const float* csrc = (r >> 9) == 0 ? s_h1 : s_h2;
    ((float4*)(out_cf + (size_t)r * H))[i] = ((const float4*)csrc)[i];
  }
}

extern "C" void kernel_launch(void* const* d_in, const int* in_sizes, int n_in,
                              void* d_out, int out_size, void* d_ws, size_t ws_size,
                              hipStream_t stream) {
  const int*   x0   = (const int*)d_in[0];
  const float* emb  = (const float*)d_in[1];
  const float* w_ih = (const float*)d_in[2];
  const float* w_hh = (const float*)d_in[3];
  const float* b_ih = (const float*)d_in[4];
  const float* b_hh = (const float*)d_in[5];
  const float* w_fc = (const float*)d_in[6];
  const float* b_fc = (const float*)d_in[7];
  float* ws = (float*)d_ws;

  hipLaunchKernelGGL(init_ws_kernel, dim3((WS_ZERO_N + 255) / 256), dim3(256), 0, stream,
                     ws, WS_ZERO_N);
  hipLaunchKernelGGL(decoder_kernel, dim3(NWG), dim3(NT), 0, stream,
                     x0, emb, w_ih, w_hh, b_ih, b_hh, w_fc, b_fc,
                     (float*)d_out, ws);
}

// Round 4
// 480.460 us; speedup vs baseline: 2.4621x; 1.0123x over previous
//
#include <hip/hip_runtime.h>
#include <math.h>

#define H 1024
#define V 18
#define NUM_NODES 7
#define LEN 40
#define BATCH 512
#define NWG 256
#define NT 1024
#define FSTRIDE 32  // u32 per flag slot = 128B line

#define AGENT __HIP_MEMORY_SCOPE_AGENT

// ws layout (floats):
//   0      h1buf [2][H]
//   2048   h2buf [2][H]
//   4096   c1buf [H]
//   5120   c2buf [H]
//   6144   flags [NWG * FSTRIDE] (u32), then rel[32] (u32)
#define FLAGS_OFF (6 * H)
#define FLAGS_N   (NWG * FSTRIDE + 32)

__device__ __forceinline__ float wred(float v) {
#pragma unroll
  for (int off = 32; off > 0; off >>= 1) v += __shfl_xor(v, off, 64);
  return v;
}
__device__ __forceinline__ float sigm(float x) { return 1.0f / (1.0f + expf(-x)); }
__device__ __forceinline__ float dot4(float4 a, float4 b) {
  return a.x * b.x + a.y * b.y + a.z * b.z + a.w * b.w;
}
#define PIN4(v) asm volatile("" : "+v"(v.x), "+v"(v.y), "+v"(v.z), "+v"(v.w))

// Two-hop fence-free barrier wait. Call from wave 0 of every WG, AFTER this
// WG's flag has been published (with stores drained via vmcnt(0)).
// WG0 wave0: sweep all flags, then publish release word. Others: poll rel.
__device__ __forceinline__ void bar_wait(unsigned* flags, unsigned* rel,
                                         int wg, int lane, unsigned k) {
  if (wg == 0) {
    for (;;) {
      bool ok = true;
#pragma unroll
      for (int m = 0; m < 4; ++m) {
        unsigned f = __hip_atomic_load(&flags[(lane + 64 * m) * FSTRIDE],
                                       __ATOMIC_RELAXED, AGENT);
        ok &= (f >= k);
      }
      if (__all(ok)) break;
      __builtin_amdgcn_s_sleep(1);
    }
    if (lane == 0) __hip_atomic_store(rel, k, __ATOMIC_RELAXED, AGENT);
  } else {
    while (__hip_atomic_load(rel, __ATOMIC_RELAXED, AGENT) < k)
      __builtin_amdgcn_s_sleep(1);
  }
}

__global__ void __launch_bounds__(256) init_ws_kernel(unsigned* p, int n) {
  int i = blockIdx.x * 256 + threadIdx.x;
  if (i < n) p[i] = 0u;
}

__global__ void __launch_bounds__(NT, 4) decoder_kernel(
    const int* __restrict__ x0,
    const float* __restrict__ emb,    // [V][H]
    const float* __restrict__ w_ih,   // [L][4H][H]
    const float* __restrict__ w_hh,   // [L][4H][H]
    const float* __restrict__ b_ih,   // [L][4H]
    const float* __restrict__ b_hh,   // [L][4H]
    const float* __restrict__ w_fc,   // [V][H]
    const float* __restrict__ b_fc,   // [V]
    float* __restrict__ out,
    float* __restrict__ ws)
{
  float* h1buf = ws;
  float* h2buf = ws + 2 * H;
  float* c1buf = ws + 4 * H;
  float* c2buf = ws + 5 * H;
  unsigned* flags = (unsigned*)(ws + FLAGS_OFF);
  unsigned* rel   = flags + NWG * FSTRIDE;

  float* out_tok  = out;                           // [LEN][BATCH] (as float)
  float* out_outs = out + LEN * BATCH;             // [BATCH][V]
  float* out_hf   = out_outs + BATCH * V;          // [2][BATCH][H]
  float* out_cf   = out_hf + 2 * BATCH * H;        // [2][BATCH][H]

  const int wg = blockIdx.x, tid = threadIdx.x;
  const int wave = tid >> 6, lane = tid & 63;
  const int q = wave & 3;          // gate (i,f,g,o)
  const int u = wave >> 2;         // unit-within-WG (0..3)
  const int j = wg * 4 + u;        // hidden unit
  const int row = q * H + j;       // gate row in a layer

  // ---- loop-resident weights (pinned in VGPRs): wh0, wi1, wh1, wfc row ----
  float4 wh0[4], wi1[4], wh1[4], wfc[4];
  {
    const float4* p1 = (const float4*)(w_hh + (size_t)row * H);
    const float4* p2 = (const float4*)(w_ih + (size_t)(4 * H + row) * H);
    const float4* p3 = (const float4*)(w_hh + (size_t)(4 * H + row) * H);
    const float4* p4 = (const float4*)(w_fc + (size_t)wave * H);  // v = wave (<16)
#pragma unroll
    for (int m = 0; m < 4; ++m) {
      wh0[m] = p1[lane + 64 * m];
      wi1[m] = p2[lane + 64 * m];
      wh1[m] = p3[lane + 64 * m];
      wfc[m] = p4[lane + 64 * m];
      PIN4(wh0[m]); PIN4(wi1[m]); PIN4(wh1[m]); PIN4(wfc[m]);
    }
  }
  const float bsum1 = b_ih[4 * H + row] + b_hh[4 * H + row];
  const float bfc_w = b_fc[wave & 15];

  __shared__ __align__(16) float s_h1[H];
  __shared__ __align__(16) float s_h2[H];
  __shared__ float s_eix[16][V];    // eix[wave][v] = wi0_row . emb[v] + bias0
  __shared__ float s_g1[4][4];
  __shared__ float s_g2[4][4];
  __shared__ float s_logits[V];
  __shared__ int s_tok;
  __shared__ float s_lse;

  // ---- prologue: fold wi0 . emb[v] for all 18 tokens (emb is constant) ----
  {
    float4 wi0[4];
    const float4* p0 = (const float4*)(w_ih + (size_t)row * H);
#pragma unroll
    for (int m = 0; m < 4; ++m) wi0[m] = p0[lane + 64 * m];
    const float bsum0 = b_ih[row] + b_hh[row];
    for (int v = 0; v < V; ++v) {
      const float4* er = (const float4*)(emb + (size_t)v * H);
      float a = 0.f;
#pragma unroll
      for (int m = 0; m < 4; ++m) a += dot4(wi0[m], er[lane + 64 * m]);
      a = wred(a);
      if (lane == 0) s_eix[wave][v] = a + bsum0;
    }
  }
  s_h1[tid] = 0.f;
  s_h2[tid] = 0.f;
  __syncthreads();

  int tok = x0[0];
  float p0 = 0.f;       // partial wh0 . h1(t-1), precomputed each step
  float c1 = 0.f, c2 = 0.f;  // cell states (live in wave0 lanes 0..3)

  for (int t = 0; t < LEN; ++t) {
    const int pw = t & 1;

    // ---- Phase A: layer 0 gates = eix[tok] + wh0.h1(t-1) (p0 ready) ----
    {
      float g0 = wred(p0);
      if (lane == 0) s_g1[u][q] = g0 + s_eix[wave][tok];
    }
    __syncthreads();
    if (wave == 0) {
      if (lane < 4) {
        const int jj = wg * 4 + lane;
        float ig = sigm(s_g1[lane][0]), fg = sigm(s_g1[lane][1]);
        float gg = tanhf(s_g1[lane][2]), og = sigm(s_g1[lane][3]);
        c1 = fg * c1 + ig * gg;
        float hn = og * tanhf(c1);
        __hip_atomic_store(&h1buf[pw * H + jj], hn, __ATOMIC_RELAXED, AGENT);
        if (t == LEN - 1)
          __hip_atomic_store(&c1buf[jj], c1, __ATOMIC_RELAXED, AGENT);
      }
      asm volatile("s_waitcnt vmcnt(0)" ::: "memory");
      if (lane == 0)
        __hip_atomic_store(&flags[wg * FSTRIDE], (unsigned)(2 * t + 1),
                           __ATOMIC_RELAXED, AGENT);
    }
    // overlap barrier A wait: partial wh1 . h2(t-1)
    float p1 = 0.f;
#pragma unroll
    for (int m = 0; m < 4; ++m)
      p1 += dot4(wh1[m], ((const float4*)s_h2)[lane + 64 * m]);
    if (wave == 0) bar_wait(flags, rel, wg, lane, (unsigned)(2 * t + 1));
    __syncthreads();
    s_h1[tid] = __hip_atomic_load(&h1buf[pw * H + tid], __ATOMIC_RELAXED, AGENT);
    __syncthreads();

    // ---- Phase B: layer 1 gates = p1 + wi1.h1(t) ----
    {
      float a = p1;
#pragma unroll
      for (int m = 0; m < 4; ++m)
        a += dot4(wi1[m], ((const float4*)s_h1)[lane + 64 * m]);
      a = wred(a);
      if (lane == 0) s_g2[u][q] = a + bsum1;
    }
    __syncthreads();
    if (wave == 0) {
      if (lane < 4) {
        const int jj = wg * 4 + lane;
        float ig = sigm(s_g2[lane][0]), fg = sigm(s_g2[lane][1]);
        float gg = tanhf(s_g2[lane][2]), og = sigm(s_g2[lane][3]);
        c2 = fg * c2 + ig * gg;
        float hn = og * tanhf(c2);
        __hip_atomic_store(&h2buf[pw * H + jj], hn, __ATOMIC_RELAXED, AGENT);
        if (t == LEN - 1)
          __hip_atomic_store(&c2buf[jj], c2, __ATOMIC_RELAXED, AGENT);
      }
      asm volatile("s_waitcnt vmcnt(0)" ::: "memory");
      if (lane == 0)
        __hip_atomic_store(&flags[wg * FSTRIDE], (unsigned)(2 * t + 2),
                           __ATOMIC_RELAXED, AGENT);
    }
    // overlap barrier B wait: next step's partial wh0 . h1(t)
    float p0n = 0.f;
#pragma unroll
    for (int m = 0; m < 4; ++m)
      p0n += dot4(wh0[m], ((const float4*)s_h1)[lane + 64 * m]);
    if (wave == 0) bar_wait(flags, rel, wg, lane, (unsigned)(2 * t + 2));
    __syncthreads();
    s_h2[tid] = __hip_atomic_load(&h2buf[pw * H + tid], __ATOMIC_RELAXED, AGENT);
    __syncthreads();
    p0 = p0n;

    // ---- Phase C: fc + argmax (redundant per WG, no grid sync) ----
    {
      {
        float a = 0.f;
#pragma unroll
        for (int m = 0; m < 4; ++m)
          a += dot4(wfc[m], ((const float4*)s_h2)[lane + 64 * m]);
        a = wred(a);
        if (lane == 0) s_logits[wave] = a + bfc_w;
      }
      if (wave < 2) {
        const int v2 = 16 + wave;
        const float4* wf = (const float4*)(w_fc + (size_t)v2 * H);
        float a = 0.f;
#pragma unroll
        for (int m = 0; m < 4; ++m)
          a += dot4(wf[lane + 64 * m], ((const float4*)s_h2)[lane + 64 * m]);
        a = wred(a);
        if (lane == 0) s_logits[v2] = a + b_fc[v2];
      }
      __syncthreads();
      if (tid == 0) {
        const int node_end = ((t >> 1) % 10) / 2 + 3;
        float bv = -INFINITY;
        int bi = 0;
        for (int v = 0; v < V; ++v) {
          bool m = (t & 1) ? (v >= NUM_NODES) : (v >= 1 && v < node_end);
          if (m && s_logits[v] > bv) { bv = s_logits[v]; bi = v; }
        }
        s_tok = bi;
      }
      __syncthreads();
      tok = s_tok;

      if (wg == 0) {
        if (tid >= 512) out_tok[t * BATCH + (tid - 512)] = (float)tok;
        if (t == LEN - 1) {
          if (tid == 0) {
            float mx = -INFINITY;
            for (int v = 0; v < V; ++v) mx = fmaxf(mx, s_logits[v]);
            float s = 0.f;
            for (int v = 0; v < V; ++v) s += expf(s_logits[v] - mx);
            s_lse = mx + logf(s);
          }
          __syncthreads();
          for (int i = tid; i < BATCH * V; i += NT)
            out_outs[i] = s_logits[i % V] - s_lse;
        }
      }
    }
  }

  // ---- Final: broadcast h_f, c_f (s_h1/s_h2 hold h(39); c published) ----
  for (int z = tid; z < 4 * (H / 4); z += NT) {
    const int rr = z >> 8;          // 0..3
    const int i  = z & 255;         // float4 index within row
    const int r  = wg + rr * NWG;   // row in [0, 1024)
    const float* hsrc = (r >> 9) == 0 ? s_h1 : s_h2;
    ((float4*)(out_hf + (size_t)r * H))[i] = ((const float4*)hsrc)[i];
  }
  __syncthreads();
  s_h1[tid] = __hip_atomic_load(&c1buf[tid], __ATOMIC_RELAXED, AGENT);
  s_h2[tid] = __hip_atomic_load(&c2buf[tid], __ATOMIC_RELAXED, AGENT);
  __syncthreads();
  for (int z = tid; z < 4 * (H / 4); z += NT) {
    const int rr = z >> 8;
    const int i  = z & 255;
    const int r  = wg + rr * NWG;
    const float* csrc = (r >> 9) == 0 ? s_h1 : s_h2;
    ((float4*)(out_cf + (size_t)r * H))[i] = ((const float4*)csrc)[i];
  }
}

extern "C" void kernel_launch(void* const* d_in, const int* in_sizes, int n_in,
                              void* d_out, int out_size, void* d_ws, size_t ws_size,
                              hipStream_t stream) {
  const int*   x0   = (const int*)d_in[0];
  const float* emb  = (const float*)d_in[1];
  const float* w_ih = (const float*)d_in[2];
  const float* w_hh = (const float*)d_in[3];
  const float* b_ih = (const float*)d_in[4];
  const float* b_hh = (const float*)d_in[5];
  const float* w_fc = (const float*)d_in[6];
  const float* b_fc = (const float*)d_in[7];
  float* ws = (float*)d_ws;

  hipLaunchKernelGGL(init_ws_kernel, dim3((FLAGS_N + 255) / 256), dim3(256), 0, stream,
                     (unsigned*)(ws + FLAGS_OFF), FLAGS_N);
  hipLaunchKernelGGL(decoder_kernel, dim3(NWG), dim3(NT), 0, stream,
                     x0, emb, w_ih, w_hh, b_ih, b_hh, w_fc, b_fc,
                     (float*)d_out, ws);
}